// Round 6
// baseline (610.007 us; speedup 1.0000x reference)
//
#include <hip/hip_runtime.h>

#define DI __device__ __forceinline__

typedef __attribute__((ext_vector_type(8))) short bf16x8;
typedef __attribute__((ext_vector_type(4))) float f32x4;
typedef __attribute__((address_space(1))) const unsigned char GAS;
typedef __attribute__((address_space(3))) unsigned char LAS;

DI unsigned short f2bf(float x) {
  unsigned int u = __builtin_bit_cast(unsigned int, x);
  u = u + 0x7fffu + ((u >> 16) & 1u);
  return (unsigned short)(u >> 16);
}
DI float bf2f(unsigned short h) {
  unsigned int u = ((unsigned int)h) << 16;
  return __builtin_bit_cast(float, u);
}

// ---- K1: prep — X->bf16, W^T, E->bf16, Lm = log2(clip(rmask)) + amask*log2e (fp16) --
__global__ __launch_bounds__(256) void prep_kernel(
    const float* __restrict__ hs, const float* __restrict__ Wq,
    const float* __restrict__ Wk, const float* __restrict__ Wv,
    const float* __restrict__ de, const float* __restrict__ rmask,
    const float* __restrict__ amask,
    unsigned short* __restrict__ Xb,   // [4096][768] bf16
    unsigned short* __restrict__ Wt,   // [2304 n][768 k] bf16
    unsigned short* __restrict__ Eb,   // [2048][64] bf16 (tail rows zero)
    _Float16* __restrict__ Lm)         // [4][1024 l][1024 r] fp16 combined bias
{
  const int bid = blockIdx.x, t = threadIdx.x;
  __shared__ unsigned short wlds[64 * 68];
  if (bid < 1536) {
    size_t base = (size_t)bid * 2048 + (size_t)t * 8;
    float4 a = *(const float4*)(hs + base);
    float4 b = *(const float4*)(hs + base + 4);
    union { unsigned short u[8]; uint4 v; } pk;
    pk.u[0]=f2bf(a.x); pk.u[1]=f2bf(a.y); pk.u[2]=f2bf(a.z); pk.u[3]=f2bf(a.w);
    pk.u[4]=f2bf(b.x); pk.u[5]=f2bf(b.y); pk.u[6]=f2bf(b.z); pk.u[7]=f2bf(b.w);
    *(uint4*)(Xb + base) = pk.v;
  } else if (bid < 1968) {
    int q = bid - 1536;
    int wi = q / 144, tile = q % 144;
    int tr = tile / 12, tc = tile % 12;
    int k0 = tr * 64, n0 = tc * 64;
    const float* W = wi == 0 ? Wq : (wi == 1 ? Wk : Wv);
    int i = t >> 2, cb = (t & 3) * 16;
    const float* src = W + (size_t)(k0 + i) * 768 + n0 + cb;
#pragma unroll
    for (int c4 = 0; c4 < 4; ++c4) {
      float4 v = *(const float4*)(src + c4 * 4);
      wlds[i * 68 + cb + c4 * 4 + 0] = f2bf(v.x);
      wlds[i * 68 + cb + c4 * 4 + 1] = f2bf(v.y);
      wlds[i * 68 + cb + c4 * 4 + 2] = f2bf(v.z);
      wlds[i * 68 + cb + c4 * 4 + 3] = f2bf(v.w);
    }
    __syncthreads();
    int n = t >> 2, ks = (t & 3) * 16;
    union { unsigned short u[16]; uint4 v[2]; } pk;
#pragma unroll
    for (int e = 0; e < 16; ++e) pk.u[e] = wlds[(ks + e) * 68 + n];
    unsigned short* dst = Wt + (size_t)wi * 589824 + (size_t)(n0 + n) * 768 + k0 + ks;
    *(uint4*)(dst) = pk.v[0];
    *(uint4*)(dst + 8) = pk.v[1];
  } else if (bid < 2032) {
    int q = bid - 1968;
    size_t base = (size_t)q * 2048 + (size_t)t * 8;
    union { unsigned short u[8]; uint4 v; } pk;
    if (base < 131008) {
      float4 a = *(const float4*)(de + base);
      float4 b = *(const float4*)(de + base + 4);
      pk.u[0]=f2bf(a.x); pk.u[1]=f2bf(a.y); pk.u[2]=f2bf(a.z); pk.u[3]=f2bf(a.w);
      pk.u[4]=f2bf(b.x); pk.u[5]=f2bf(b.y); pk.u[6]=f2bf(b.z); pk.u[7]=f2bf(b.w);
    } else {
      pk.v = uint4{0u, 0u, 0u, 0u};
    }
    *(uint4*)(Eb + base) = pk.v;
  } else {
    int q = bid - 2032;  // 0..2047
    size_t base = (size_t)q * 2048 + (size_t)t * 8;
    int b = (int)(base >> 20);
    int r = (int)(base & 1023);
    float4 a = *(const float4*)(rmask + base);
    float4 bb = *(const float4*)(rmask + base + 4);
    float4 m0 = *(const float4*)(amask + b * 1024 + r);
    float4 m1 = *(const float4*)(amask + b * 1024 + r + 4);
    const float L2E = 1.4426950408889634f;
    union { _Float16 h[8]; uint4 v; } pk;
    pk.h[0] = (_Float16)(__log2f(fmaxf(a.x, 1e-5f)) + m0.x * L2E);
    pk.h[1] = (_Float16)(__log2f(fmaxf(a.y, 1e-5f)) + m0.y * L2E);
    pk.h[2] = (_Float16)(__log2f(fmaxf(a.z, 1e-5f)) + m0.z * L2E);
    pk.h[3] = (_Float16)(__log2f(fmaxf(a.w, 1e-5f)) + m0.w * L2E);
    pk.h[4] = (_Float16)(__log2f(fmaxf(bb.x, 1e-5f)) + m1.x * L2E);
    pk.h[5] = (_Float16)(__log2f(fmaxf(bb.y, 1e-5f)) + m1.y * L2E);
    pk.h[6] = (_Float16)(__log2f(fmaxf(bb.z, 1e-5f)) + m1.z * L2E);
    pk.h[7] = (_Float16)(__log2f(fmaxf(bb.w, 1e-5f)) + m1.w * L2E);
    *(uint4*)(Lm + base) = pk.v;
  }
}

// ---- K2: fused QKV GEMM [4096 x 2304 x 768], 128x128 tile, gload_lds ---------------
__global__ __launch_bounds__(256) void proj_kernel(
    const unsigned short* __restrict__ Xb, const unsigned short* __restrict__ Wt,
    const float* __restrict__ bq, const float* __restrict__ bk, const float* __restrict__ bv,
    unsigned short* __restrict__ Qb, unsigned short* __restrict__ Kb,
    unsigned short* __restrict__ Vb)
{
  const int x = blockIdx.x, y = blockIdx.y;
  const int t = threadIdx.x, w = t >> 6, lane = t & 63, g = lane >> 4, ln = lane & 15;
  const int wm = w >> 1, wn = w & 1;
  __shared__ __align__(16) unsigned char smem[32768];
  unsigned char* sA = smem;
  unsigned char* sB = smem + 16384;
  const int m0 = x * 128, n0 = y * 128;
  const int sec = y / 6, hb = (y % 6) * 2 + wn;
  const float* bias = sec == 0 ? bq : (sec == 1 ? bk : bv);
  unsigned short* Out = sec == 0 ? Qb : (sec == 1 ? Kb : Vb);
  const unsigned char* Xbb = (const unsigned char*)Xb;
  const unsigned char* Wtb = (const unsigned char*)Wt;

  f32x4 acc[4][4];
#pragma unroll
  for (int a = 0; a < 4; ++a)
#pragma unroll
    for (int c = 0; c < 4; ++c) acc[a][c] = f32x4{0.f, 0.f, 0.f, 0.f};

  for (int kt = 0; kt < 12; ++kt) {
    __syncthreads();
#pragma unroll
    for (int ci = 0; ci < 4; ++ci) {
      int idx = ci * 1024 + lane * 16;
      int rl = idx >> 7, col = idx & 127;
      int row = w * 32 + rl;
      int scol = col ^ ((row & 7) << 4);
      __builtin_amdgcn_global_load_lds(
          (const GAS*)(Xbb + (size_t)(m0 + row) * 1536 + kt * 128 + scol),
          (LAS*)(sA + w * 4096 + ci * 1024), 16, 0, 0);
      __builtin_amdgcn_global_load_lds(
          (const GAS*)(Wtb + (size_t)(n0 + row) * 1536 + kt * 128 + scol),
          (LAS*)(sB + w * 4096 + ci * 1024), 16, 0, 0);
    }
    __syncthreads();
    bf16x8 af[4][2], bfr[4][2];
#pragma unroll
    for (int ms = 0; ms < 4; ++ms) {
      int row = wm * 64 + ms * 16 + ln;
#pragma unroll
      for (int ks = 0; ks < 2; ++ks)
        af[ms][ks] = *(const bf16x8*)(sA + ((row * 128 + ks * 64 + g * 16) ^ ((row & 7) << 4)));
    }
#pragma unroll
    for (int c = 0; c < 4; ++c) {
      int row = wn * 64 + c * 16 + ln;
#pragma unroll
      for (int ks = 0; ks < 2; ++ks)
        bfr[c][ks] = *(const bf16x8*)(sB + ((row * 128 + ks * 64 + g * 16) ^ ((row & 7) << 4)));
    }
#pragma unroll
    for (int ms = 0; ms < 4; ++ms)
#pragma unroll
      for (int c = 0; c < 4; ++c) {
        acc[ms][c] = __builtin_amdgcn_mfma_f32_16x16x32_bf16(af[ms][0], bfr[c][0], acc[ms][c], 0, 0, 0);
        acc[ms][c] = __builtin_amdgcn_mfma_f32_16x16x32_bf16(af[ms][1], bfr[c][1], acc[ms][c], 0, 0, 0);
      }
  }
  float b4[4];
#pragma unroll
  for (int c = 0; c < 4; ++c) b4[c] = bias[hb * 64 + c * 16 + ln];
#pragma unroll
  for (int ms = 0; ms < 4; ++ms)
#pragma unroll
    for (int c = 0; c < 4; ++c)
#pragma unroll
      for (int jj = 0; jj < 4; ++jj) {
        int m = m0 + wm * 64 + ms * 16 + g * 4 + jj;
        int bb = m >> 10, s = m & 1023;
        float v = acc[ms][c][jj] + b4[c];
        Out[((size_t)(bb * 12 + hb) * 1024 + s) * 64 + c * 16 + ln] = f2bf(v);
      }
}

// ---- K3: V -> V^T ------------------------------------------------------------------
__global__ __launch_bounds__(256) void vtrans_kernel(
    const unsigned short* __restrict__ Vb, unsigned short* __restrict__ Vtb)
{
  const int s0 = blockIdx.x * 256, bh = blockIdx.y, t = threadIdx.x;
  __shared__ __align__(16) unsigned short lds[256 * 64];
  const unsigned short* src = Vb + ((size_t)bh * 1024 + s0 + t) * 64;
#pragma unroll
  for (int gi = 0; gi < 8; ++gi) {
    uint4 v = *(const uint4*)(src + gi * 8);
    *(uint4*)((unsigned char*)lds + t * 128 + ((gi ^ (t & 7)) << 4)) = v;
  }
  __syncthreads();
  const int d = t >> 2, seg = t & 3;
  unsigned short* dst = Vtb + ((size_t)bh * 64 + d) * 1024 + s0 + seg * 64;
#pragma unroll
  for (int ck = 0; ck < 8; ++ck) {
    union { unsigned short u[8]; uint4 v; } pk;
#pragma unroll
    for (int e = 0; e < 8; ++e) {
      int sl = seg * 64 + ck * 8 + e;
      pk.u[e] = lds[sl * 64 + (((d >> 3) ^ (sl & 7)) << 3) + (d & 7)];
    }
    *(uint4*)(dst + ck * 8) = pk.v;
  }
}

// ---- K4: fused attention. QBLK=128 (8 waves), KVBLK=64, 4-way r-split ---------------
// LDS: sK 8K | sV 8K | Ht [192 j][68 r] 26.1K | per-wave Gt [80][20] / P overlay 8x3264
__global__ __launch_bounds__(512, 4) void attn_kernel(
    const _Float16* __restrict__ Lm,
    const unsigned short* __restrict__ Qb, const unsigned short* __restrict__ Kb,
    const unsigned short* __restrict__ Vtb, const unsigned short* __restrict__ Eb,
    _Float16* __restrict__ pctx, float* __restrict__ pm)
{
  const int orig = blockIdx.x;
  const int wg = (orig & 7) * 192 + (orig >> 3);  // XCD-contiguous remap (1536 = 8*192)
  const int h = wg % 12;
  const int grp = wg / 12;                         // 0..127, 12 heads share each grp
  const int split = grp & 3, lb = (grp >> 2) & 7, b = grp >> 5;
  const int bh = b * 12 + h, l0 = lb * 128;
  const int t = threadIdx.x, w = t >> 6, lane = t & 63, g = lane >> 4, ln = lane & 15;
  __shared__ __align__(16) unsigned char smem[68608];
  unsigned char* sK = smem;                               // [64 r][64 k] swz
  unsigned char* sV = smem + 8192;                        // [64 d][64 r] swz
  unsigned short* Ht = (unsigned short*)(smem + 16384);   // [192 j][68 r-cols]
  unsigned short* Gtw = (unsigned short*)(smem + 42496 + w * 3264);  // [80 j][20 l]
  unsigned char* Pw = (unsigned char*)Gtw;                // overlay [16 l][64 r] swz

  const unsigned short* Qrow = Qb + ((size_t)bh * 1024 + l0 + w * 16 + ln) * 64;
  const bf16x8 qa0 = *(const bf16x8*)(Qrow + g * 8);
  const bf16x8 qa1 = *(const bf16x8*)(Qrow + 32 + g * 8);

  bf16x8 ones;
#pragma unroll
  for (int i = 0; i < 8; ++i) ones[i] = (short)0x3F80;

  f32x4 ctx[4], ctx5;
#pragma unroll
  for (int c = 0; c < 4; ++c) ctx[c] = f32x4{0.f, 0.f, 0.f, 0.f};
  ctx5 = f32x4{0.f, 0.f, 0.f, 0.f};
  float mrun[4] = {-1e30f, -1e30f, -1e30f, -1e30f};

  const unsigned char* Kbase = (const unsigned char*)(Kb + (size_t)bh * 65536);
  const unsigned char* Vbase = (const unsigned char*)(Vtb + (size_t)bh * 65536);
  const int itBeg = split * 4, itEnd = itBeg + 4;

  const int sp = t * 16, srow = sp >> 7, scol = sp & 127;  // 512 thr cover [64][128B]
  uint4 kp, vp;
  kp = *(const uint4*)(Kbase + (size_t)(itBeg * 64 + srow) * 128 + scol);
  vp = *(const uint4*)(Vbase + (size_t)srow * 2048 + itBeg * 128 + scol);

  for (int it = itBeg; it < itEnd; ++it) {
    const int r0 = it * 64;
    __syncthreads();  // (A) prev readers of sK/sV/Ht done
    {
      int ad = sp ^ ((srow & 7) << 4);
      *(uint4*)(sK + ad) = kp;
      *(uint4*)(sV + ad) = vp;
    }
    if (it + 1 < itEnd) {
      kp = *(const uint4*)(Kbase + (size_t)(r0 + 64 + srow) * 128 + scol);
      vp = *(const uint4*)(Vbase + (size_t)srow * 2048 + (r0 + 64) * 2 + scol);
    }
    // ---- G phase (wave-private, no LDS dep): G[l][j]=q[l].E[D0+j], c = w..w+4
    const int D0 = l0 - r0 + 960;
#pragma unroll
    for (int cc = 0; cc < 5; ++cc) {
      int c = w + cc;
      const unsigned short* Erow = Eb + (size_t)(D0 + c * 16 + ln) * 64;
      bf16x8 e0 = *(const bf16x8*)(Erow + g * 8);
      bf16x8 e1 = *(const bf16x8*)(Erow + 32 + g * 8);
      f32x4 ga = f32x4{0.f, 0.f, 0.f, 0.f};
      ga = __builtin_amdgcn_mfma_f32_16x16x32_bf16(qa0, e0, ga, 0, 0, 0);
      ga = __builtin_amdgcn_mfma_f32_16x16x32_bf16(qa1, e1, ga, 0, 0, 0);
      ushort4 pk = {f2bf(ga[0]), f2bf(ga[1]), f2bf(ga[2]), f2bf(ga[3])};
      *(ushort4*)(Gtw + (cc * 16 + ln) * 20 + g * 4) = pk;
    }
    __syncthreads();  // (B) sK/sV visible
    // K fragments (shared by QK and H: A-frag layout == B-frag layout)
    bf16x8 kb[4][2];
#pragma unroll
    for (int c = 0; c < 4; ++c)
#pragma unroll
      for (int ks = 0; ks < 2; ++ks) {
        int row = c * 16 + ln;
        kb[c][ks] = *(const bf16x8*)(sK + ((row * 128 + ks * 64 + g * 16) ^ ((row & 7) << 4)));
      }
    // combined-mask prefetch (consumed in softmax)
    float lmf[4][4];
    {
      const _Float16* lrow = Lm + (size_t)b * 1048576 +
                             (size_t)(l0 + w * 16 + g * 4) * 1024 + r0;
#pragma unroll
      for (int jj = 0; jj < 4; ++jj)
#pragma unroll
        for (int ct = 0; ct < 4; ++ct)
          lmf[ct][jj] = (float)lrow[(size_t)jj * 1024 + ct * 16 + ln];
    }
    // ---- H phase: H[r][j]=k[r].E[D0+j]; wave w: r-strip w>>1, 4-5 j-tiles
    {
      const int rt = w >> 1;
      const int kbeg = (w & 1) ? 5 : 0, kend = (w & 1) ? 9 : 5;
#pragma unroll
      for (int k = kbeg; k < kend; ++k) {
        int c = 3 - rt + k;
        const unsigned short* Erow = Eb + (size_t)(D0 + c * 16 + ln) * 64;
        bf16x8 e0 = *(const bf16x8*)(Erow + g * 8);
        bf16x8 e1 = *(const bf16x8*)(Erow + 32 + g * 8);
        f32x4 hac = f32x4{0.f, 0.f, 0.f, 0.f};
        hac = __builtin_amdgcn_mfma_f32_16x16x32_bf16(kb[rt][0], e0, hac, 0, 0, 0);
        hac = __builtin_amdgcn_mfma_f32_16x16x32_bf16(kb[rt][1], e1, hac, 0, 0, 0);
        ushort4 pk = {f2bf(hac[0]), f2bf(hac[1]), f2bf(hac[2]), f2bf(hac[3])};
        *(ushort4*)(Ht + (size_t)(c * 16 + ln) * 68 + rt * 16 + g * 4) = pk;
      }
    }
    __syncthreads();  // (C) Ht visible
    // ---- bias gather into C, QK^T on top
    f32x4 sacc[4];
#pragma unroll
    for (int ct = 0; ct < 4; ++ct) {
      int rlb = ct * 16 + ln;
      f32x4 si;
#pragma unroll
      for (int jj = 0; jj < 4; ++jj) {
        int lloc = g * 4 + jj;
        si[jj] = bf2f(Gtw[(lloc - rlb + 63) * 20 + lloc]) +
                 bf2f(Ht[(size_t)(w * 16 + lloc - rlb + 63) * 68 + rlb]);
      }
      sacc[ct] = si;
      sacc[ct] = __builtin_amdgcn_mfma_f32_16x16x32_bf16(qa0, kb[ct][0], sacc[ct], 0, 0, 0);
      sacc[ct] = __builtin_amdgcn_mfma_f32_16x16x32_bf16(qa1, kb[ct][1], sacc[ct], 0, 0, 0);
    }
    // ---- online softmax (log2 domain, mask additive, in-place on sacc)
    float rmax[4];
#pragma unroll
    for (int jj = 0; jj < 4; ++jj) {
#pragma unroll
      for (int ct = 0; ct < 4; ++ct)
        sacc[ct][jj] = sacc[ct][jj] * 0.1803368801f + lmf[ct][jj];
      float rv = fmaxf(fmaxf(sacc[0][jj], sacc[1][jj]), fmaxf(sacc[2][jj], sacc[3][jj]));
#pragma unroll
      for (int mm = 1; mm < 16; mm <<= 1) rv = fmaxf(rv, __shfl_xor(rv, mm));
      rmax[jj] = rv;
    }
    float sf[4];
#pragma unroll
    for (int jj = 0; jj < 4; ++jj) {
      float mnew = fmaxf(mrun[jj], rmax[jj]);
      sf[jj] = __builtin_amdgcn_exp2f(mrun[jj] - mnew);
      mrun[jj] = mnew;
    }
    unsigned short pb[4][4];
#pragma unroll
    for (int ct = 0; ct < 4; ++ct)
#pragma unroll
      for (int jj = 0; jj < 4; ++jj)
        pb[ct][jj] = f2bf(__builtin_amdgcn_exp2f(sacc[ct][jj] - mrun[jj]));
#pragma unroll
    for (int c = 0; c < 4; ++c)
#pragma unroll
      for (int jj = 0; jj < 4; ++jj) ctx[c][jj] *= sf[jj];
#pragma unroll
    for (int jj = 0; jj < 4; ++jj) ctx5[jj] *= sf[jj];
    // ---- P -> wave-private LDS (overlays Gt; in-wave order makes this safe)
#pragma unroll
    for (int ct = 0; ct < 4; ++ct)
#pragma unroll
      for (int jj = 0; jj < 4; ++jj) {
        int lp = g * 4 + jj;
        *(unsigned short*)(Pw + ((lp * 128 + (ct * 16 + ln) * 2) ^ ((lp & 7) << 4))) = pb[ct][jj];
      }
    bf16x8 pa0, pa1;
    {
      int lr = ln;
      pa0 = *(const bf16x8*)(Pw + ((lr * 128 + g * 16) ^ ((lr & 7) << 4)));
      pa1 = *(const bf16x8*)(Pw + ((lr * 128 + 64 + g * 16) ^ ((lr & 7) << 4)));
    }
    // ---- PV + sigma (ones-column) from LDS-staged V^T
#pragma unroll
    for (int cd = 0; cd < 4; ++cd) {
      int row = cd * 16 + ln;
      bf16x8 v0 = *(const bf16x8*)(sV + ((row * 128 + g * 16) ^ ((row & 7) << 4)));
      bf16x8 v1 = *(const bf16x8*)(sV + ((row * 128 + 64 + g * 16) ^ ((row & 7) << 4)));
      ctx[cd] = __builtin_amdgcn_mfma_f32_16x16x32_bf16(pa0, v0, ctx[cd], 0, 0, 0);
      ctx[cd] = __builtin_amdgcn_mfma_f32_16x16x32_bf16(pa1, v1, ctx[cd], 0, 0, 0);
    }
    ctx5 = __builtin_amdgcn_mfma_f32_16x16x32_bf16(pa0, ones, ctx5, 0, 0, 0);
    ctx5 = __builtin_amdgcn_mfma_f32_16x16x32_bf16(pa1, ones, ctx5, 0, 0, 0);
  }
  // ---- write fp16 partials + (m, sigma)
  const size_t rowb = (size_t)split * 49152 + (size_t)bh * 1024 + l0 + w * 16;
#pragma unroll
  for (int cd = 0; cd < 4; ++cd)
#pragma unroll
    for (int jj = 0; jj < 4; ++jj)
      pctx[(rowb + g * 4 + jj) * 64 + cd * 16 + ln] = (_Float16)ctx[cd][jj];
  if (ln == 0) {
#pragma unroll
    for (int jj = 0; jj < 4; ++jj) {
      size_t rr = rowb + g * 4 + jj;
      pm[rr * 2] = mrun[jj];
      pm[rr * 2 + 1] = ctx5[jj];
    }
  }
}

// ---- K5: combine 4 r-splits --------------------------------------------------------
__global__ __launch_bounds__(256) void combine_kernel(
    const _Float16* __restrict__ pctx, const float* __restrict__ pm,
    float* __restrict__ out)
{
  int tid = blockIdx.x * 256 + threadIdx.x;  // 393216
  int row = tid >> 3, d0 = (tid & 7) * 8;
  int bh = row >> 10, l = row & 1023, b = bh / 12, hh = bh % 12;
  float m[4], s[4];
#pragma unroll
  for (int sp = 0; sp < 4; ++sp) {
    size_t rr = (size_t)sp * 49152 + row;
    m[sp] = pm[rr * 2];
    s[sp] = pm[rr * 2 + 1];
  }
  float M = fmaxf(fmaxf(m[0], m[1]), fmaxf(m[2], m[3]));
  float wv[4], denom = 0.f;
#pragma unroll
  for (int sp = 0; sp < 4; ++sp) {
    wv[sp] = __builtin_amdgcn_exp2f(m[sp] - M);
    denom += wv[sp] * s[sp];
  }
  float inv = 1.f / denom;
  float o[8] = {0.f, 0.f, 0.f, 0.f, 0.f, 0.f, 0.f, 0.f};
#pragma unroll
  for (int sp = 0; sp < 4; ++sp) {
    const _Float16* src = pctx + ((size_t)sp * 49152 + row) * 64 + d0;
    union { uint4 v; _Float16 h[8]; } u;
    u.v = *(const uint4*)src;
#pragma unroll
    for (int e = 0; e < 8; ++e) o[e] += wv[sp] * (float)u.h[e];
  }
  float* dst = out + (size_t)(b * 1024 + l) * 768 + hh * 64 + d0;
  float4 o0 = {o[0] * inv, o[1] * inv, o[2] * inv, o[3] * inv};
  float4 o1 = {o[4] * inv, o[5] * inv, o[6] * inv, o[7] * inv};
  *(float4*)dst = o0;
  *(float4*)(dst + 4) = o1;
}

extern "C" void kernel_launch(void* const* d_in, const int* in_sizes, int n_in,
                              void* d_out, int out_size, void* d_ws, size_t ws_size,
                              hipStream_t stream) {
  const float* hs    = (const float*)d_in[0];
  const float* amask = (const float*)d_in[1];
  const float* rmask = (const float*)d_in[2];
  const float* Wq    = (const float*)d_in[3];
  const float* bq    = (const float*)d_in[4];
  const float* Wk    = (const float*)d_in[5];
  const float* bk    = (const float*)d_in[6];
  const float* Wv    = (const float*)d_in[7];
  const float* bv    = (const float*)d_in[8];
  const float* de    = (const float*)d_in[9];
  unsigned char* ws = (unsigned char*)d_ws;
  // pctx (25.2 MB fp16) overlays Xb/Wt/Vb (all dead before attn runs)
  _Float16*       pctx = (_Float16*)(ws + 0);              // 25165824 B
  unsigned short* Xb   = (unsigned short*)(ws + 0);        //  6291456 B
  unsigned short* Wt   = (unsigned short*)(ws + 6291456);  //  3538944 B
  unsigned short* Vb   = (unsigned short*)(ws + 9830400);  //  6291456 B
  unsigned short* Eb   = (unsigned short*)(ws + 25165824); //   262144 B
  unsigned short* Qb   = (unsigned short*)(ws + 25427968); //  6291456 B
  unsigned short* Kb   = (unsigned short*)(ws + 31719424); //  6291456 B
  unsigned short* Vtb  = (unsigned short*)(ws + 38010880); //  6291456 B
  _Float16*       Lm   = (_Float16*)(ws + 44302336);       //  8388608 B
  float*          pm   = (float*)(ws + 52690944);          //  1572864 B (end 54.3 MB)
  float* out = (float*)d_out;

  hipLaunchKernelGGL(prep_kernel, dim3(4080), dim3(256), 0, stream,
                     hs, Wq, Wk, Wv, de, rmask, amask, Xb, Wt, Eb, Lm);
  hipLaunchKernelGGL(proj_kernel, dim3(32, 18), dim3(256), 0, stream,
                     Xb, Wt, bq, bk, bv, Qb, Kb, Vb);
  hipLaunchKernelGGL(vtrans_kernel, dim3(4, 48), dim3(256), 0, stream, Vb, Vtb);
  hipLaunchKernelGGL(attn_kernel, dim3(1536), dim3(512), 0, stream,
                     Lm, Qb, Kb, Vtb, Eb, pctx, pm);
  hipLaunchKernelGGL(combine_kernel, dim3(1536), dim3(256), 0, stream, pctx, pm, out);
}

// Round 8
// 316.117 us; speedup vs baseline: 1.9297x; 1.9297x over previous
//
#include <hip/hip_runtime.h>

#define DI __device__ __forceinline__

typedef __attribute__((ext_vector_type(8))) short bf16x8;
typedef __attribute__((ext_vector_type(4))) float f32x4;
typedef __attribute__((address_space(1))) const unsigned char GAS;
typedef __attribute__((address_space(3))) unsigned char LAS;

DI unsigned short f2bf(float x) {
  unsigned int u = __builtin_bit_cast(unsigned int, x);
  u = u + 0x7fffu + ((u >> 16) & 1u);
  return (unsigned short)(u >> 16);
}
DI float bf2f(unsigned short h) {
  unsigned int u = ((unsigned int)h) << 16;
  return __builtin_bit_cast(float, u);
}

// ---- K1: prep — X->bf16, W^T, E->bf16, Lm = log2(clip(rmask)) + amask*log2e (fp16) --
__global__ __launch_bounds__(256) void prep_kernel(
    const float* __restrict__ hs, const float* __restrict__ Wq,
    const float* __restrict__ Wk, const float* __restrict__ Wv,
    const float* __restrict__ de, const float* __restrict__ rmask,
    const float* __restrict__ amask,
    unsigned short* __restrict__ Xb,   // [4096][768] bf16
    unsigned short* __restrict__ Wt,   // [2304 n][768 k] bf16
    unsigned short* __restrict__ Eb,   // [2048][64] bf16 (tail rows zero)
    _Float16* __restrict__ Lm)         // [4][1024 l][1024 r] fp16 combined bias
{
  const int bid = blockIdx.x, t = threadIdx.x;
  __shared__ unsigned short wlds[64 * 68];
  if (bid < 1536) {
    size_t base = (size_t)bid * 2048 + (size_t)t * 8;
    float4 a = *(const float4*)(hs + base);
    float4 b = *(const float4*)(hs + base + 4);
    union { unsigned short u[8]; uint4 v; } pk;
    pk.u[0]=f2bf(a.x); pk.u[1]=f2bf(a.y); pk.u[2]=f2bf(a.z); pk.u[3]=f2bf(a.w);
    pk.u[4]=f2bf(b.x); pk.u[5]=f2bf(b.y); pk.u[6]=f2bf(b.z); pk.u[7]=f2bf(b.w);
    *(uint4*)(Xb + base) = pk.v;
  } else if (bid < 1968) {
    int q = bid - 1536;
    int wi = q / 144, tile = q % 144;
    int tr = tile / 12, tc = tile % 12;
    int k0 = tr * 64, n0 = tc * 64;
    const float* W = wi == 0 ? Wq : (wi == 1 ? Wk : Wv);
    int i = t >> 2, cb = (t & 3) * 16;
    const float* src = W + (size_t)(k0 + i) * 768 + n0 + cb;
#pragma unroll
    for (int c4 = 0; c4 < 4; ++c4) {
      float4 v = *(const float4*)(src + c4 * 4);
      wlds[i * 68 + cb + c4 * 4 + 0] = f2bf(v.x);
      wlds[i * 68 + cb + c4 * 4 + 1] = f2bf(v.y);
      wlds[i * 68 + cb + c4 * 4 + 2] = f2bf(v.z);
      wlds[i * 68 + cb + c4 * 4 + 3] = f2bf(v.w);
    }
    __syncthreads();
    int n = t >> 2, ks = (t & 3) * 16;
    union { unsigned short u[16]; uint4 v[2]; } pk;
#pragma unroll
    for (int e = 0; e < 16; ++e) pk.u[e] = wlds[(ks + e) * 68 + n];
    unsigned short* dst = Wt + (size_t)wi * 589824 + (size_t)(n0 + n) * 768 + k0 + ks;
    *(uint4*)(dst) = pk.v[0];
    *(uint4*)(dst + 8) = pk.v[1];
  } else if (bid < 2032) {
    int q = bid - 1968;
    size_t base = (size_t)q * 2048 + (size_t)t * 8;
    union { unsigned short u[8]; uint4 v; } pk;
    if (base < 131008) {
      float4 a = *(const float4*)(de + base);
      float4 b = *(const float4*)(de + base + 4);
      pk.u[0]=f2bf(a.x); pk.u[1]=f2bf(a.y); pk.u[2]=f2bf(a.z); pk.u[3]=f2bf(a.w);
      pk.u[4]=f2bf(b.x); pk.u[5]=f2bf(b.y); pk.u[6]=f2bf(b.z); pk.u[7]=f2bf(b.w);
    } else {
      pk.v = uint4{0u, 0u, 0u, 0u};
    }
    *(uint4*)(Eb + base) = pk.v;
  } else {
    int q = bid - 2032;  // 0..2047
    size_t base = (size_t)q * 2048 + (size_t)t * 8;
    int b = (int)(base >> 20);
    int r = (int)(base & 1023);
    float4 a = *(const float4*)(rmask + base);
    float4 bb = *(const float4*)(rmask + base + 4);
    float4 m0 = *(const float4*)(amask + b * 1024 + r);
    float4 m1 = *(const float4*)(amask + b * 1024 + r + 4);
    const float L2E = 1.4426950408889634f;
    union { _Float16 h[8]; uint4 v; } pk;
    pk.h[0] = (_Float16)(__log2f(fmaxf(a.x, 1e-5f)) + m0.x * L2E);
    pk.h[1] = (_Float16)(__log2f(fmaxf(a.y, 1e-5f)) + m0.y * L2E);
    pk.h[2] = (_Float16)(__log2f(fmaxf(a.z, 1e-5f)) + m0.z * L2E);
    pk.h[3] = (_Float16)(__log2f(fmaxf(a.w, 1e-5f)) + m0.w * L2E);
    pk.h[4] = (_Float16)(__log2f(fmaxf(bb.x, 1e-5f)) + m1.x * L2E);
    pk.h[5] = (_Float16)(__log2f(fmaxf(bb.y, 1e-5f)) + m1.y * L2E);
    pk.h[6] = (_Float16)(__log2f(fmaxf(bb.z, 1e-5f)) + m1.z * L2E);
    pk.h[7] = (_Float16)(__log2f(fmaxf(bb.w, 1e-5f)) + m1.w * L2E);
    *(uint4*)(Lm + base) = pk.v;
  }
}

// ---- K2: fused QKV GEMM [4096 x 2304 x 768], 128x128 tile, gload_lds ---------------
__global__ __launch_bounds__(256) void proj_kernel(
    const unsigned short* __restrict__ Xb, const unsigned short* __restrict__ Wt,
    const float* __restrict__ bq, const float* __restrict__ bk, const float* __restrict__ bv,
    unsigned short* __restrict__ Qb, unsigned short* __restrict__ Kb,
    unsigned short* __restrict__ Vb)
{
  const int x = blockIdx.x, y = blockIdx.y;
  const int t = threadIdx.x, w = t >> 6, lane = t & 63, g = lane >> 4, ln = lane & 15;
  const int wm = w >> 1, wn = w & 1;
  __shared__ __align__(16) unsigned char smem[32768];
  unsigned char* sA = smem;
  unsigned char* sB = smem + 16384;
  const int m0 = x * 128, n0 = y * 128;
  const int sec = y / 6, hb = (y % 6) * 2 + wn;
  const float* bias = sec == 0 ? bq : (sec == 1 ? bk : bv);
  unsigned short* Out = sec == 0 ? Qb : (sec == 1 ? Kb : Vb);
  const unsigned char* Xbb = (const unsigned char*)Xb;
  const unsigned char* Wtb = (const unsigned char*)Wt;

  f32x4 acc[4][4];
#pragma unroll
  for (int a = 0; a < 4; ++a)
#pragma unroll
    for (int c = 0; c < 4; ++c) acc[a][c] = f32x4{0.f, 0.f, 0.f, 0.f};

  for (int kt = 0; kt < 12; ++kt) {
    __syncthreads();
#pragma unroll
    for (int ci = 0; ci < 4; ++ci) {
      int idx = ci * 1024 + lane * 16;
      int rl = idx >> 7, col = idx & 127;
      int row = w * 32 + rl;
      int scol = col ^ ((row & 7) << 4);
      __builtin_amdgcn_global_load_lds(
          (const GAS*)(Xbb + (size_t)(m0 + row) * 1536 + kt * 128 + scol),
          (LAS*)(sA + w * 4096 + ci * 1024), 16, 0, 0);
      __builtin_amdgcn_global_load_lds(
          (const GAS*)(Wtb + (size_t)(n0 + row) * 1536 + kt * 128 + scol),
          (LAS*)(sB + w * 4096 + ci * 1024), 16, 0, 0);
    }
    __syncthreads();
    bf16x8 af[4][2], bfr[4][2];
#pragma unroll
    for (int ms = 0; ms < 4; ++ms) {
      int row = wm * 64 + ms * 16 + ln;
#pragma unroll
      for (int ks = 0; ks < 2; ++ks)
        af[ms][ks] = *(const bf16x8*)(sA + ((row * 128 + ks * 64 + g * 16) ^ ((row & 7) << 4)));
    }
#pragma unroll
    for (int c = 0; c < 4; ++c) {
      int row = wn * 64 + c * 16 + ln;
#pragma unroll
      for (int ks = 0; ks < 2; ++ks)
        bfr[c][ks] = *(const bf16x8*)(sB + ((row * 128 + ks * 64 + g * 16) ^ ((row & 7) << 4)));
    }
#pragma unroll
    for (int ms = 0; ms < 4; ++ms)
#pragma unroll
      for (int c = 0; c < 4; ++c) {
        acc[ms][c] = __builtin_amdgcn_mfma_f32_16x16x32_bf16(af[ms][0], bfr[c][0], acc[ms][c], 0, 0, 0);
        acc[ms][c] = __builtin_amdgcn_mfma_f32_16x16x32_bf16(af[ms][1], bfr[c][1], acc[ms][c], 0, 0, 0);
      }
  }
  float b4[4];
#pragma unroll
  for (int c = 0; c < 4; ++c) b4[c] = bias[hb * 64 + c * 16 + ln];
#pragma unroll
  for (int ms = 0; ms < 4; ++ms)
#pragma unroll
    for (int c = 0; c < 4; ++c)
#pragma unroll
      for (int jj = 0; jj < 4; ++jj) {
        int m = m0 + wm * 64 + ms * 16 + g * 4 + jj;
        int bb = m >> 10, s = m & 1023;
        float v = acc[ms][c][jj] + b4[c];
        Out[((size_t)(bb * 12 + hb) * 1024 + s) * 64 + c * 16 + ln] = f2bf(v);
      }
}

// ---- K3: V -> V^T ------------------------------------------------------------------
__global__ __launch_bounds__(256) void vtrans_kernel(
    const unsigned short* __restrict__ Vb, unsigned short* __restrict__ Vtb)
{
  const int s0 = blockIdx.x * 256, bh = blockIdx.y, t = threadIdx.x;
  __shared__ __align__(16) unsigned short lds[256 * 64];
  const unsigned short* src = Vb + ((size_t)bh * 1024 + s0 + t) * 64;
#pragma unroll
  for (int gi = 0; gi < 8; ++gi) {
    uint4 v = *(const uint4*)(src + gi * 8);
    *(uint4*)((unsigned char*)lds + t * 128 + ((gi ^ (t & 7)) << 4)) = v;
  }
  __syncthreads();
  const int d = t >> 2, seg = t & 3;
  unsigned short* dst = Vtb + ((size_t)bh * 64 + d) * 1024 + s0 + seg * 64;
#pragma unroll
  for (int ck = 0; ck < 8; ++ck) {
    union { unsigned short u[8]; uint4 v; } pk;
#pragma unroll
    for (int e = 0; e < 8; ++e) {
      int sl = seg * 64 + ck * 8 + e;
      pk.u[e] = lds[sl * 64 + (((d >> 3) ^ (sl & 7)) << 3) + (d & 7)];
    }
    *(uint4*)(dst + ck * 8) = pk.v;
  }
}

// ---- K4: fused attention (round-5 skeleton, 4-way r-split, ones-sigma, fp16 pctx) ---
// LDS: sK 8K | sV 8K | Ht [128 j][68 r] 17K | per-wave Gt[80][20] / P overlay 4x3264
__global__ __launch_bounds__(256, 2) void attn_kernel(
    const _Float16* __restrict__ Lm,
    const unsigned short* __restrict__ Qb, const unsigned short* __restrict__ Kb,
    const unsigned short* __restrict__ Vtb, const unsigned short* __restrict__ Eb,
    _Float16* __restrict__ pctx, float* __restrict__ pm)
{
  const int orig = blockIdx.x;
  const int wg = (orig & 7) * 384 + (orig >> 3);  // XCD-contiguous remap (3072 = 8*384)
  const int h = wg % 12;
  const int grp = wg / 12;                        // 0..255; 12 heads share each grp
  const int split = grp & 3, lb = (grp >> 2) & 15, b = grp >> 6;
  const int bh = b * 12 + h, l0 = lb * 64;
  const int t = threadIdx.x, w = t >> 6, lane = t & 63, g = lane >> 4, ln = lane & 15;
  __shared__ __align__(16) unsigned char smem[46848];
  unsigned char* sK = smem;                                  // [64 r][64 k] swz
  unsigned char* sV = smem + 8192;                           // [64 d][64 r] swz
  unsigned short* Ht = (unsigned short*)(smem + 16384);      // [128 j][68 r-cols]
  unsigned short* Gtw = (unsigned short*)(smem + 33792 + w * 3264);  // [80 j][20 l]
  unsigned char* Pw = (unsigned char*)Gtw;                   // overlay [16 l][64 r] swz

  const unsigned short* Qrow = Qb + ((size_t)bh * 1024 + l0 + w * 16 + ln) * 64;
  const bf16x8 qa0 = *(const bf16x8*)(Qrow + g * 8);
  const bf16x8 qa1 = *(const bf16x8*)(Qrow + 32 + g * 8);

  bf16x8 ones;
#pragma unroll
  for (int i = 0; i < 8; ++i) ones[i] = (short)0x3F80;

  f32x4 ctx[4], ctx5;
#pragma unroll
  for (int c = 0; c < 4; ++c) ctx[c] = f32x4{0.f, 0.f, 0.f, 0.f};
  ctx5 = f32x4{0.f, 0.f, 0.f, 0.f};
  float mrun[4] = {-1e30f, -1e30f, -1e30f, -1e30f};

  const unsigned char* Kbase = (const unsigned char*)(Kb + (size_t)bh * 65536);
  const unsigned char* Vbase = (const unsigned char*)(Vtb + (size_t)bh * 65536);
  const int itBeg = split * 4, itEnd = itBeg + 4;

  const int sp = t * 16, srow = sp >> 7, scol = sp & 127;  // srow 0..31
  uint4 kp[2], vp[2];
#pragma unroll
  for (int i = 0; i < 2; ++i) {
    kp[i] = *(const uint4*)(Kbase + (size_t)(itBeg * 64 + srow + i * 32) * 128 + scol);
    vp[i] = *(const uint4*)(Vbase + (size_t)(srow + i * 32) * 2048 + itBeg * 128 + scol);
  }

  for (int it = itBeg; it < itEnd; ++it) {
    const int r0 = it * 64;
    __syncthreads();  // (A) prev readers of sK/sV done
#pragma unroll
    for (int i = 0; i < 2; ++i) {
      int p = i * 4096 + sp, row = p >> 7;
      int ad = p ^ ((row & 7) << 4);
      *(uint4*)(sK + ad) = kp[i];
      *(uint4*)(sV + ad) = vp[i];
    }
    if (it + 1 < itEnd) {
#pragma unroll
      for (int i = 0; i < 2; ++i) {
        kp[i] = *(const uint4*)(Kbase + (size_t)(r0 + 64 + srow + i * 32) * 128 + scol);
        vp[i] = *(const uint4*)(Vbase + (size_t)(srow + i * 32) * 2048 + (r0 + 64) * 2 + scol);
      }
    }
    // combined-mask prefetch (fp16; consumed in softmax far below)
    float lmf[4][4];
    {
      const _Float16* lrow = Lm + (size_t)b * 1048576 +
                             (size_t)(l0 + w * 16 + g * 4) * 1024 + r0;
#pragma unroll
      for (int jj = 0; jj < 4; ++jj)
#pragma unroll
        for (int ct = 0; ct < 4; ++ct)
          lmf[ct][jj] = (float)lrow[(size_t)jj * 1024 + ct * 16 + ln];
    }
    // ---- G phase (wave-private): G[l][j] = q[l].E[D0+j], j-tiles c = w..w+4
    const int D0 = l0 - r0 + 960;
#pragma unroll
    for (int cc = 0; cc < 5; ++cc) {
      int c = w + cc;
      const unsigned short* Erow = Eb + (size_t)(D0 + c * 16 + ln) * 64;
      bf16x8 e0 = *(const bf16x8*)(Erow + g * 8);
      bf16x8 e1 = *(const bf16x8*)(Erow + 32 + g * 8);
      f32x4 ga = f32x4{0.f, 0.f, 0.f, 0.f};
      ga = __builtin_amdgcn_mfma_f32_16x16x32_bf16(qa0, e0, ga, 0, 0, 0);
      ga = __builtin_amdgcn_mfma_f32_16x16x32_bf16(qa1, e1, ga, 0, 0, 0);
      ushort4 pk = {f2bf(ga[0]), f2bf(ga[1]), f2bf(ga[2]), f2bf(ga[3])};
      *(ushort4*)(Gtw + (cc * 16 + ln) * 20 + g * 4) = pk;
    }
    __syncthreads();  // (B) sK/sV staged + visible
    // K fragments (shared by QK B-operand and H A-operand)
    bf16x8 kb[4][2];
#pragma unroll
    for (int c = 0; c < 4; ++c)
#pragma unroll
      for (int ks = 0; ks < 2; ++ks) {
        int row = c * 16 + ln;
        kb[c][ks] = *(const bf16x8*)(sK + ((row * 128 + ks * 64 + g * 16) ^ ((row & 7) << 4)));
      }
    bf16x8 ha0, ha1;
    {
      int row = w * 16 + ln;
      ha0 = *(const bf16x8*)(sK + ((row * 128 + g * 16) ^ ((row & 7) << 4)));
      ha1 = *(const bf16x8*)(sK + ((row * 128 + 64 + g * 16) ^ ((row & 7) << 4)));
    }
    // ---- H phase: H[r][j] = k[r].E[D0+j]; own r-rows, j-tiles c in [3-w, 7-w]
#pragma unroll
    for (int cc = 0; cc < 5; ++cc) {
      int c = 3 - w + cc;
      const unsigned short* Erow = Eb + (size_t)(D0 + c * 16 + ln) * 64;
      bf16x8 e0 = *(const bf16x8*)(Erow + g * 8);
      bf16x8 e1 = *(const bf16x8*)(Erow + 32 + g * 8);
      f32x4 hac = f32x4{0.f, 0.f, 0.f, 0.f};
      hac = __builtin_amdgcn_mfma_f32_16x16x32_bf16(ha0, e0, hac, 0, 0, 0);
      hac = __builtin_amdgcn_mfma_f32_16x16x32_bf16(ha1, e1, hac, 0, 0, 0);
      ushort4 pk = {f2bf(hac[0]), f2bf(hac[1]), f2bf(hac[2]), f2bf(hac[3])};
      *(ushort4*)(Ht + (size_t)(c * 16 + ln) * 68 + w * 16 + g * 4) = pk;
    }
    __syncthreads();  // (C) Ht visible
    // ---- bias gather into C, QK^T on top
    f32x4 sacc[4];
#pragma unroll
    for (int ct = 0; ct < 4; ++ct) {
      int rlb = ct * 16 + ln;
      f32x4 si;
#pragma unroll
      for (int jj = 0; jj < 4; ++jj) {
        int lloc = g * 4 + jj;
        si[jj] = bf2f(Gtw[(lloc - rlb + 63) * 20 + lloc]) +
                 bf2f(Ht[(size_t)(w * 16 + lloc - rlb + 63) * 68 + rlb]);
      }
      sacc[ct] = si;
    }
    __builtin_amdgcn_s_setprio(1);
#pragma unroll
    for (int ct = 0; ct < 4; ++ct) {
      sacc[ct] = __builtin_amdgcn_mfma_f32_16x16x32_bf16(qa0, kb[ct][0], sacc[ct], 0, 0, 0);
      sacc[ct] = __builtin_amdgcn_mfma_f32_16x16x32_bf16(qa1, kb[ct][1], sacc[ct], 0, 0, 0);
    }
    __builtin_amdgcn_s_setprio(0);
    // ---- online softmax (log2 domain, mask additive)
    float rmax[4];
#pragma unroll
    for (int jj = 0; jj < 4; ++jj) {
#pragma unroll
      for (int ct = 0; ct < 4; ++ct)
        sacc[ct][jj] = sacc[ct][jj] * 0.1803368801f + lmf[ct][jj];
      float rv = fmaxf(fmaxf(sacc[0][jj], sacc[1][jj]), fmaxf(sacc[2][jj], sacc[3][jj]));
#pragma unroll
      for (int mm = 1; mm < 16; mm <<= 1) rv = fmaxf(rv, __shfl_xor(rv, mm));
      rmax[jj] = rv;
    }
    float sf[4];
#pragma unroll
    for (int jj = 0; jj < 4; ++jj) {
      float mnew = fmaxf(mrun[jj], rmax[jj]);
      sf[jj] = __builtin_amdgcn_exp2f(mrun[jj] - mnew);
      mrun[jj] = mnew;
    }
    unsigned short pb[4][4];
#pragma unroll
    for (int ct = 0; ct < 4; ++ct)
#pragma unroll
      for (int jj = 0; jj < 4; ++jj)
        pb[ct][jj] = f2bf(__builtin_amdgcn_exp2f(sacc[ct][jj] - mrun[jj]));
#pragma unroll
    for (int c = 0; c < 4; ++c)
#pragma unroll
      for (int jj = 0; jj < 4; ++jj) ctx[c][jj] *= sf[jj];
#pragma unroll
    for (int jj = 0; jj < 4; ++jj) ctx5[jj] *= sf[jj];
    // ---- P -> wave-private LDS (overlays Gt; in-wave data order makes this safe)
#pragma unroll
    for (int ct = 0; ct < 4; ++ct)
#pragma unroll
      for (int jj = 0; jj < 4; ++jj) {
        int lp = g * 4 + jj;
        *(unsigned short*)(Pw + ((lp * 128 + (ct * 16 + ln) * 2) ^ ((lp & 7) << 4))) = pb[ct][jj];
      }
    bf16x8 pa0, pa1;
    {
      int lr = ln;
      pa0 = *(const bf16x8*)(Pw + ((lr * 128 + g * 16) ^ ((lr & 7) << 4)));
      pa1 = *(const bf16x8*)(Pw + ((lr * 128 + 64 + g * 16) ^ ((lr & 7) << 4)));
    }
    // ---- PV + sigma (ones-column) from LDS-staged V^T
    __builtin_amdgcn_s_setprio(1);
#pragma unroll
    for (int cd = 0; cd < 4; ++cd) {
      int row = cd * 16 + ln;
      bf16x8 v0 = *(const bf16x8*)(sV + ((row * 128 + g * 16) ^ ((row & 7) << 4)));
      bf16x8 v1 = *(const bf16x8*)(sV + ((row * 128 + 64 + g * 16) ^ ((row & 7) << 4)));
      ctx[cd] = __builtin_amdgcn_mfma_f32_16x16x32_bf16(pa0, v0, ctx[cd], 0, 0, 0);
      ctx[cd] = __builtin_amdgcn_mfma_f32_16x16x32_bf16(pa1, v1, ctx[cd], 0, 0, 0);
    }
    ctx5 = __builtin_amdgcn_mfma_f32_16x16x32_bf16(pa0, ones, ctx5, 0, 0, 0);
    ctx5 = __builtin_amdgcn_mfma_f32_16x16x32_bf16(pa1, ones, ctx5, 0, 0, 0);
    __builtin_amdgcn_s_setprio(0);
  }
  // ---- write fp16 partials + (m, sigma)
  const size_t rowb = (size_t)split * 49152 + (size_t)bh * 1024 + l0 + w * 16;
#pragma unroll
  for (int cd = 0; cd < 4; ++cd)
#pragma unroll
    for (int jj = 0; jj < 4; ++jj)
      pctx[(rowb + g * 4 + jj) * 64 + cd * 16 + ln] = (_Float16)ctx[cd][jj];
  if (ln == 0) {
#pragma unroll
    for (int jj = 0; jj < 4; ++jj) {
      size_t rr = rowb + g * 4 + jj;
      pm[rr * 2] = mrun[jj];
      pm[rr * 2 + 1] = ctx5[jj];
    }
  }
}

// ---- K5: combine 4 r-splits --------------------------------------------------------
__global__ __launch_bounds__(256) void combine_kernel(
    const _Float16* __restrict__ pctx, const float* __restrict__ pm,
    float* __restrict__ out)
{
  int tid = blockIdx.x * 256 + threadIdx.x;  // 393216
  int row = tid >> 3, d0 = (tid & 7) * 8;
  int bh = row >> 10, l = row & 1023, b = bh / 12, hh = bh % 12;
  float m[4], s[4];
#pragma unroll
  for (int sp = 0; sp < 4; ++sp) {
    size_t rr = (size_t)sp * 49152 + row;
    m[sp] = pm[rr * 2];
    s[sp] = pm[rr * 2 + 1];
  }
  float M = fmaxf(fmaxf(m[0], m[1]), fmaxf(m[2], m[3]));
  float wv[4], denom = 0.f;
#pragma unroll
  for (int sp = 0; sp < 4; ++sp) {
    wv[sp] = __builtin_amdgcn_exp2f(m[sp] - M);
    denom += wv[sp] * s[sp];
  }
  float inv = 1.f / denom;
  float o[8] = {0.f, 0.f, 0.f, 0.f, 0.f, 0.f, 0.f, 0.f};
#pragma unroll
  for (int sp = 0; sp < 4; ++sp) {
    const _Float16* src = pctx + ((size_t)sp * 49152 + row) * 64 + d0;
    union { uint4 v; _Float16 h[8]; } u;
    u.v = *(const uint4*)src;
#pragma unroll
    for (int e = 0; e < 8; ++e) o[e] += wv[sp] * (float)u.h[e];
  }
  float* dst = out + (size_t)(b * 1024 + l) * 768 + hh * 64 + d0;
  float4 o0 = {o[0] * inv, o[1] * inv, o[2] * inv, o[3] * inv};
  float4 o1 = {o[4] * inv, o[5] * inv, o[6] * inv, o[7] * inv};
  *(float4*)dst = o0;
  *(float4*)(dst + 4) = o1;
}

extern "C" void kernel_launch(void* const* d_in, const int* in_sizes, int n_in,
                              void* d_out, int out_size, void* d_ws, size_t ws_size,
                              hipStream_t stream) {
  const float* hs    = (const float*)d_in[0];
  const float* amask = (const float*)d_in[1];
  const float* rmask = (const float*)d_in[2];
  const float* Wq    = (const float*)d_in[3];
  const float* bq    = (const float*)d_in[4];
  const float* Wk    = (const float*)d_in[5];
  const float* bk    = (const float*)d_in[6];
  const float* Wv    = (const float*)d_in[7];
  const float* bv    = (const float*)d_in[8];
  const float* de    = (const float*)d_in[9];
  unsigned char* ws = (unsigned char*)d_ws;
  // pctx (25.2 MB fp16) overlays Xb/Wt/Vb (all dead before attn runs)
  _Float16*       pctx = (_Float16*)(ws + 0);              // 25165824 B
  unsigned short* Xb   = (unsigned short*)(ws + 0);        //  6291456 B
  unsigned short* Wt   = (unsigned short*)(ws + 6291456);  //  3538944 B
  unsigned short* Vb   = (unsigned short*)(ws + 9830400);  //  6291456 B
  unsigned short* Eb   = (unsigned short*)(ws + 25165824); //   262144 B
  unsigned short* Qb   = (unsigned short*)(ws + 25427968); //  6291456 B
  unsigned short* Kb   = (unsigned short*)(ws + 31719424); //  6291456 B
  unsigned short* Vtb  = (unsigned short*)(ws + 38010880); //  6291456 B
  _Float16*       Lm   = (_Float16*)(ws + 44302336);       //  8388608 B
  float*          pm   = (float*)(ws + 52690944);          //  1572864 B (end 54.3 MB)
  float* out = (float*)d_out;

  hipLaunchKernelGGL(prep_kernel, dim3(4080), dim3(256), 0, stream,
                     hs, Wq, Wk, Wv, de, rmask, amask, Xb, Wt, Eb, Lm);
  hipLaunchKernelGGL(proj_kernel, dim3(32, 18), dim3(256), 0, stream,
                     Xb, Wt, bq, bk, bv, Qb, Kb, Vb);
  hipLaunchKernelGGL(vtrans_kernel, dim3(4, 48), dim3(256), 0, stream, Vb, Vtb);
  hipLaunchKernelGGL(attn_kernel, dim3(3072), dim3(256), 0, stream,
                     Lm, Qb, Kb, Vtb, Eb, pctx, pm);
  hipLaunchKernelGGL(combine_kernel, dim3(1536), dim3(256), 0, stream, pctx, pm, out);
}